// Round 1
// baseline (11019.609 us; speedup 1.0000x reference)
//
#include <hip/hip_runtime.h>
#include <stdint.h>

#define Tt 1024
#define Bt 128
#define Vt 256

typedef __attribute__((ext_vector_type(8))) short bf16x8;
typedef __attribute__((ext_vector_type(4))) float f32x4;

__device__ __forceinline__ unsigned short f2bf(float f) {
    unsigned u = __builtin_bit_cast(unsigned, f);
    u += 0x7fffu + ((u >> 16) & 1u);
    return (unsigned short)(u >> 16);
}
__device__ __forceinline__ float sigm(float x) { return 1.f / (1.f + __expf(-x)); }
__device__ __forceinline__ float tanh_f(float x) {
    float e = __expf(-2.f * fabsf(x));
    float t = (1.f - e) / (1.f + e);
    return copysignf(t, x);
}

// ---------------- x [B,T,V] fp32 -> xT [T,B,V] bf16 ----------------
__global__ __launch_bounds__(256) void cvt_kernel(const float* __restrict__ x,
                                                  unsigned short* __restrict__ xT) {
    unsigned g = blockIdx.x * 256u + threadIdx.x;
    unsigned base = g * 8u;
    unsigned r = base >> 8;      // r = t*128 + b
    unsigned v = base & 255u;
    unsigned t = r >> 7, b = r & 127u;
    const float4* src = (const float4*)(x + ((size_t)b * Tt + t) * Vt + v);
    float4 f0 = src[0], f1 = src[1];
    union { unsigned short s[8]; int4 q; } o;
    o.s[0] = f2bf(f0.x); o.s[1] = f2bf(f0.y); o.s[2] = f2bf(f0.z); o.s[3] = f2bf(f0.w);
    o.s[4] = f2bf(f1.x); o.s[5] = f2bf(f1.y); o.s[6] = f2bf(f1.z); o.s[7] = f2bf(f1.w);
    *(int4*)(xT + (size_t)r * Vt + v) = o.q;
}

// ---------------- persistent dataflow recurrence: 64 WGs ----------------
// wg 0..31  : layer 1, owns h-cols [8*sub, 8*sub+8)  (32 gate cols)
// wg 32..63 : layer 2, same partitioning
// h exchanged via agent-scope atomics through MALL; per-t 32-bit arrival masks.
__global__ __launch_bounds__(256) void rec_kernel(
    const float* __restrict__ Wih1, const float* __restrict__ Whh1,
    const float* __restrict__ bih1, const float* __restrict__ bhh1,
    const float* __restrict__ Wih2, const float* __restrict__ Whh2,
    const float* __restrict__ bih2, const float* __restrict__ bhh2,
    const unsigned short* __restrict__ xT,
    unsigned short* h1s, unsigned short* h2s,
    unsigned int* flags1, unsigned int* flags2) {
    const int wg = blockIdx.x;
    const int layer = wg >> 5;
    const int sub = wg & 31;
    const int hc0 = sub * 8;
    const float* Win = layer ? Wih2 : Wih1;
    const float* Whh = layer ? Whh2 : Whh1;
    const float* bi = layer ? bih2 : bih1;
    const float* bh = layer ? bhh2 : bhh1;

    // LDS row lr: grp = lr>>3 (i,f,g,o), local col = lr&7 ; global W row = 256*grp + hc0 + local
    __shared__ unsigned short sWin[32][264];  // +8 shorts pad per row: bank-conflict-safe ds_read_b128
    __shared__ unsigned short sWhh[32][264];

    const int tid = threadIdx.x;
    {
        int m = tid >> 7;            // 0: Win, 1: Whh
        int lr = (tid >> 2) & 31;
        int seg = tid & 3;
        int grp = lr >> 3, local = lr & 7;
        int grow = 256 * grp + hc0 + local;
        const float* src = (m ? Whh : Win) + (size_t)grow * Vt + seg * 64;
        unsigned short* dst = m ? &sWhh[lr][seg * 64] : &sWin[lr][seg * 64];
        for (int k = 0; k < 64; k += 4) {
            float4 f = *(const float4*)(src + k);
            dst[k + 0] = f2bf(f.x); dst[k + 1] = f2bf(f.y);
            dst[k + 2] = f2bf(f.z); dst[k + 3] = f2bf(f.w);
        }
    }
    __syncthreads();

    const int lane = tid & 63;
    const int w = tid >> 6;          // wave 0..3 -> batch rows [32w, 32w+32)
    const int q = lane >> 4;
    const int ln = lane & 15;

    float biasv[2];
    for (int nb = 0; nb < 2; ++nb) {
        int grp = nb * 2 + (ln >> 3);
        int grow = 256 * grp + hc0 + (ln & 7);
        biasv[nb] = bi[grow] + bh[grow];
    }

    float cst[2][4];
    for (int rb = 0; rb < 2; ++rb)
        for (int r = 0; r < 4; ++r) cst[rb][r] = 0.f;

    // per-lane A-frag offsets (in shorts) within one t-slice
    const int rowoff0 = (32 * w + ln) * 256 + q * 8;
    const int rowoff1 = rowoff0 + 16 * 256;
    const unsigned int FULL = 0xffffffffu;

    unsigned short* obbase = layer ? h2s : h1s;
    unsigned int* myflags = layer ? flags2 : flags1;

    for (int t = 0; t < Tt; ++t) {
        f32x4 acc[2][2];
        for (int rb = 0; rb < 2; ++rb)
            for (int nb = 0; nb < 2; ++nb)
                acc[rb][nb] = (f32x4){biasv[nb], biasv[nb], biasv[nb], biasv[nb]};

        bf16x8 ain[2][8];
        bf16x8 ah[2][8];
        bool have_h = (t > 0);

        if (layer == 0) {
            // issue x loads first (overlaps the flag wait)
            const unsigned short* xp = xT + (size_t)t * (Bt * Vt);
            for (int kb = 0; kb < 8; ++kb) {
                ain[0][kb] = *(const bf16x8*)(xp + rowoff0 + kb * 32);
                ain[1][kb] = *(const bf16x8*)(xp + rowoff1 + kb * 32);
            }
            if (t > 0) {
                while (__hip_atomic_load(&flags1[t - 1], __ATOMIC_RELAXED,
                                         __HIP_MEMORY_SCOPE_AGENT) != FULL)
                    __builtin_amdgcn_s_sleep(2);
                asm volatile("" ::: "memory");
                unsigned long long* hp =
                    (unsigned long long*)(h1s + (size_t)(t - 1) * (Bt * Vt));
                for (int rb = 0; rb < 2; ++rb)
                    for (int kb = 0; kb < 8; ++kb) {
                        int off = ((rb ? rowoff1 : rowoff0) + kb * 32) >> 2;
                        union { unsigned long long u[2]; bf16x8 v; } tmp;
                        tmp.u[0] = __hip_atomic_load(hp + off, __ATOMIC_RELAXED,
                                                     __HIP_MEMORY_SCOPE_AGENT);
                        tmp.u[1] = __hip_atomic_load(hp + off + 1, __ATOMIC_RELAXED,
                                                     __HIP_MEMORY_SCOPE_AGENT);
                        ah[rb][kb] = tmp.v;
                    }
            }
        } else {
            while (__hip_atomic_load(&flags1[t], __ATOMIC_RELAXED,
                                     __HIP_MEMORY_SCOPE_AGENT) != FULL)
                __builtin_amdgcn_s_sleep(2);
            asm volatile("" ::: "memory");
            unsigned long long* hp1 = (unsigned long long*)(h1s + (size_t)t * (Bt * Vt));
            for (int rb = 0; rb < 2; ++rb)
                for (int kb = 0; kb < 8; ++kb) {
                    int off = ((rb ? rowoff1 : rowoff0) + kb * 32) >> 2;
                    union { unsigned long long u[2]; bf16x8 v; } tmp;
                    tmp.u[0] = __hip_atomic_load(hp1 + off, __ATOMIC_RELAXED,
                                                 __HIP_MEMORY_SCOPE_AGENT);
                    tmp.u[1] = __hip_atomic_load(hp1 + off + 1, __ATOMIC_RELAXED,
                                                 __HIP_MEMORY_SCOPE_AGENT);
                    ain[rb][kb] = tmp.v;
                }
            if (t > 0) {
                while (__hip_atomic_load(&flags2[t - 1], __ATOMIC_RELAXED,
                                         __HIP_MEMORY_SCOPE_AGENT) != FULL)
                    __builtin_amdgcn_s_sleep(2);
                asm volatile("" ::: "memory");
                unsigned long long* hp2 =
                    (unsigned long long*)(h2s + (size_t)(t - 1) * (Bt * Vt));
                for (int rb = 0; rb < 2; ++rb)
                    for (int kb = 0; kb < 8; ++kb) {
                        int off = ((rb ? rowoff1 : rowoff0) + kb * 32) >> 2;
                        union { unsigned long long u[2]; bf16x8 v; } tmp;
                        tmp.u[0] = __hip_atomic_load(hp2 + off, __ATOMIC_RELAXED,
                                                     __HIP_MEMORY_SCOPE_AGENT);
                        tmp.u[1] = __hip_atomic_load(hp2 + off + 1, __ATOMIC_RELAXED,
                                                     __HIP_MEMORY_SCOPE_AGENT);
                        ah[rb][kb] = tmp.v;
                    }
            }
        }

        // input-projection GEMM
        for (int kb = 0; kb < 8; ++kb) {
            bf16x8 b0 = *(const bf16x8*)&sWin[ln][kb * 32 + q * 8];
            bf16x8 b1 = *(const bf16x8*)&sWin[16 + ln][kb * 32 + q * 8];
            acc[0][0] = __builtin_amdgcn_mfma_f32_16x16x32_bf16(ain[0][kb], b0, acc[0][0], 0, 0, 0);
            acc[1][0] = __builtin_amdgcn_mfma_f32_16x16x32_bf16(ain[1][kb], b0, acc[1][0], 0, 0, 0);
            acc[0][1] = __builtin_amdgcn_mfma_f32_16x16x32_bf16(ain[0][kb], b1, acc[0][1], 0, 0, 0);
            acc[1][1] = __builtin_amdgcn_mfma_f32_16x16x32_bf16(ain[1][kb], b1, acc[1][1], 0, 0, 0);
        }
        // recurrent GEMM
        if (have_h) {
            for (int kb = 0; kb < 8; ++kb) {
                bf16x8 b0 = *(const bf16x8*)&sWhh[ln][kb * 32 + q * 8];
                bf16x8 b1 = *(const bf16x8*)&sWhh[16 + ln][kb * 32 + q * 8];
                acc[0][0] = __builtin_amdgcn_mfma_f32_16x16x32_bf16(ah[0][kb], b0, acc[0][0], 0, 0, 0);
                acc[1][0] = __builtin_amdgcn_mfma_f32_16x16x32_bf16(ah[1][kb], b0, acc[1][0], 0, 0, 0);
                acc[0][1] = __builtin_amdgcn_mfma_f32_16x16x32_bf16(ah[0][kb], b1, acc[0][1], 0, 0, 0);
                acc[1][1] = __builtin_amdgcn_mfma_f32_16x16x32_bf16(ah[1][kb], b1, acc[1][1], 0, 0, 0);
            }
        }

        // elementwise LSTM cell; lane ln holds (i|f) in acc[.][0], (g|o) in acc[.][1]
        unsigned short* ob = obbase + (size_t)t * (Bt * Vt);
        for (int rb = 0; rb < 2; ++rb) {
            for (int r = 0; r < 4; ++r) {
                float a0 = acc[rb][0][r], a1 = acc[rb][1][r];
                float b0 = __shfl_xor(a0, 8);
                float b1 = __shfl_xor(a1, 8);
                float iv, fv, gv, ov;
                if (ln < 8) { iv = a0; fv = b0; gv = a1; ov = b1; }
                else        { iv = b0; fv = a0; gv = b1; ov = a1; }
                float ii = sigm(iv), ff = sigm(fv), gg = tanh_f(gv), oo = sigm(ov);
                float cc = ff * cst[rb][r] + ii * gg;
                cst[rb][r] = cc;
                float hh = oo * tanh_f(cc);
                if (ln < 8) {
                    size_t off = (size_t)(32 * w + rb * 16 + q * 4 + r) * 256 + hc0 + ln;
                    __hip_atomic_store(ob + off, f2bf(hh), __ATOMIC_RELAXED,
                                       __HIP_MEMORY_SCOPE_AGENT);
                }
            }
        }

        asm volatile("s_waitcnt vmcnt(0)" ::: "memory");
        __syncthreads();
        if (tid == 0) {
            asm volatile("" ::: "memory");
            __hip_atomic_fetch_or(&myflags[t], 1u << sub, __ATOMIC_RELAXED,
                                  __HIP_MEMORY_SCOPE_AGENT);
        }
    }
}

// ---------------- out[b,t,:] = h2s[t,b,:] @ w_n^T + fc_b ----------------
__global__ __launch_bounds__(256) void fc_kernel(const unsigned short* __restrict__ h2s,
                                                 const float* __restrict__ fcw,
                                                 const float* __restrict__ fcb,
                                                 float* __restrict__ out) {
    const int bid = blockIdx.x;
    const int rb = bid >> 2;             // t
    const int c0 = (bid & 3) * 64;
    __shared__ unsigned short sW[64][264];
    __shared__ float sInv[64];
    const int tid = threadIdx.x;
    if (tid < 64) {
        const float* wr = fcw + (size_t)(c0 + tid) * 256;
        float s = 0.f;
        for (int k = 0; k < 256; k += 4) {
            float4 f = *(const float4*)(wr + k);
            s += f.x * f.x + f.y * f.y + f.z * f.z + f.w * f.w;
        }
        sInv[tid] = rsqrtf(s);
    }
    __syncthreads();
    {
        int lr = tid & 63, seg = tid >> 6;
        float inv = sInv[lr];
        const float* wr = fcw + (size_t)(c0 + lr) * 256 + seg * 64;
        unsigned short* dst = &sW[lr][seg * 64];
        for (int k = 0; k < 64; k += 4) {
            float4 f = *(const float4*)(wr + k);
            dst[k + 0] = f2bf(f.x * inv); dst[k + 1] = f2bf(f.y * inv);
            dst[k + 2] = f2bf(f.z * inv); dst[k + 3] = f2bf(f.w * inv);
        }
    }
    __syncthreads();
    const int lane = tid & 63, w = tid >> 6, q = lane >> 4, ln = lane & 15;
    f32x4 acc[2][4];
    for (int rk = 0; rk < 2; ++rk)
        for (int nb = 0; nb < 4; ++nb) {
            float bv = fcb[c0 + nb * 16 + ln];
            acc[rk][nb] = (f32x4){bv, bv, bv, bv};
        }
    const unsigned short* ap = h2s + (size_t)rb * (Bt * Vt);
    for (int kb = 0; kb < 8; ++kb) {
        bf16x8 a0 = *(const bf16x8*)(ap + (32 * w + ln) * 256 + kb * 32 + q * 8);
        bf16x8 a1 = *(const bf16x8*)(ap + (32 * w + 16 + ln) * 256 + kb * 32 + q * 8);
        for (int nb = 0; nb < 4; ++nb) {
            bf16x8 b = *(const bf16x8*)&sW[nb * 16 + ln][kb * 32 + q * 8];
            acc[0][nb] = __builtin_amdgcn_mfma_f32_16x16x32_bf16(a0, b, acc[0][nb], 0, 0, 0);
            acc[1][nb] = __builtin_amdgcn_mfma_f32_16x16x32_bf16(a1, b, acc[1][nb], 0, 0, 0);
        }
    }
    for (int rk = 0; rk < 2; ++rk)
        for (int nb = 0; nb < 4; ++nb)
            for (int r = 0; r < 4; ++r) {
                int bb = 32 * w + rk * 16 + q * 4 + r;
                int o = c0 + nb * 16 + ln;
                out[((size_t)bb * Tt + rb) * 256 + o] = acc[rk][nb][r];
            }
}

extern "C" void kernel_launch(void* const* d_in, const int* in_sizes, int n_in,
                              void* d_out, int out_size, void* d_ws, size_t ws_size,
                              hipStream_t stream) {
    const float* x    = (const float*)d_in[0];
    const float* Wih1 = (const float*)d_in[1];
    const float* Whh1 = (const float*)d_in[2];
    const float* bih1 = (const float*)d_in[3];
    const float* bhh1 = (const float*)d_in[4];
    const float* Wih2 = (const float*)d_in[5];
    const float* Whh2 = (const float*)d_in[6];
    const float* bih2 = (const float*)d_in[7];
    const float* bhh2 = (const float*)d_in[8];
    const float* fcw  = (const float*)d_in[9];
    const float* fcb  = (const float*)d_in[10];

    char* ws = (char*)d_ws;
    unsigned int* flags1 = (unsigned int*)ws;
    unsigned int* flags2 = flags1 + Tt;
    unsigned short* xT  = (unsigned short*)(ws + 16384);
    unsigned short* h1s = xT + (size_t)Tt * Bt * Vt;
    unsigned short* h2s = h1s + (size_t)Tt * Bt * Vt;

    hipMemsetAsync(ws, 0, 16384, stream);
    cvt_kernel<<<16384, 256, 0, stream>>>(x, xT);
    rec_kernel<<<64, 256, 0, stream>>>(Wih1, Whh1, bih1, bhh1,
                                       Wih2, Whh2, bih2, bhh2,
                                       xT, h1s, h2s, flags1, flags2);
    fc_kernel<<<4096, 256, 0, stream>>>(h2s, fcw, fcb, (float*)d_out);
}